// Round 1
// baseline (5872.846 us; speedup 1.0000x reference)
//
#include <hip/hip_runtime.h>
#include <hip/hip_bf16.h>
#include <math.h>

// WReN forward: loss + acc.
// Decomposition:
//   emb = x(8192,6400) @ W_emb + b_emb                         (GEMM)
//   U[k] = emb[k]@Wg1[0:512]   + Wg1[512+min(k,8)]  + bg1      (GEMM + tag-row epilogue)
//   V[k] = emb[k]@Wg1[521:1033]+ Wg1[1033+min(k,8)]            (GEMM + tag-row epilogue)
//   H1[b,p] = relu(U[b, p&7] + V[b, p>>3])   p in [0,128)      (pair build; p<64 ctx pairs, p>=64 cc pairs)
//   H2 = relu(H1 @ Wg2 + bg2); G = relu(H2 @ Wg3 + bg3)        (big GEMMs, G overwrites H1)
//   rel[b,a] = sum_{p<64} G[b,p] + sum_j G[b,64+a*8+j]
//   HF = relu(rel @ Wf1 + bf1); f = HF @ Wf2 + bf2
//   loss = mean BCE-with-logits vs one-hot; acc = mean(argmax==label)

#define TMg 128
#define TNg 128
#define TKg 16

__global__ __launch_bounds__(256) void gemm_f32(
    const float* __restrict__ A, int lda,
    const float* __restrict__ Bm, int ldb,
    float* __restrict__ C, int ldc,
    int M, int N, int K,
    const float* __restrict__ bias,   // per-column bias or null
    const float* __restrict__ tagW,   // row-indexed extra bias (ld = ldb): + tagW[min(m%16,8)*ldb + n], or null
    int relu)
{
    __shared__ float As[TKg][TMg];
    __shared__ float Bs[TKg][TNg];
    const int tid = threadIdx.x;
    const int tx = tid & 15;   // 0..15 col group
    const int ty = tid >> 4;   // 0..15 row group
    const int row0 = blockIdx.y * TMg;
    const int col0 = blockIdx.x * TNg;

    // staging maps
    const int am  = tid >> 1;         // 0..127
    const int ak0 = (tid & 1) << 3;   // 0 or 8
    const int bk  = tid >> 4;         // 0..15
    const int bn0 = (tid & 15) << 3;  // 0..120

    float acc[8][8];
    #pragma unroll
    for (int i = 0; i < 8; ++i)
        #pragma unroll
        for (int j = 0; j < 8; ++j) acc[i][j] = 0.f;

    for (int k0 = 0; k0 < K; k0 += TKg) {
        // ---- A tile: As[k][m] ----
        {
            int gm = row0 + am;
            const float* Ap = A + (size_t)gm * lda + (k0 + ak0);
            if (gm < M && k0 + TKg <= K) {
                // lda and k offsets are even -> float2 is 8B-aligned
                float2 v0 = *(const float2*)(Ap + 0);
                float2 v1 = *(const float2*)(Ap + 2);
                float2 v2 = *(const float2*)(Ap + 4);
                float2 v3 = *(const float2*)(Ap + 6);
                As[ak0+0][am] = v0.x; As[ak0+1][am] = v0.y;
                As[ak0+2][am] = v1.x; As[ak0+3][am] = v1.y;
                As[ak0+4][am] = v2.x; As[ak0+5][am] = v2.y;
                As[ak0+6][am] = v3.x; As[ak0+7][am] = v3.y;
            } else {
                #pragma unroll
                for (int i = 0; i < 8; ++i) {
                    int gk = k0 + ak0 + i;
                    As[ak0+i][am] = (gm < M && gk < K) ? Ap[i] : 0.f;
                }
            }
        }
        // ---- B tile: Bs[k][n] ----
        {
            int gk = k0 + bk;
            const float* Bp = Bm + (size_t)gk * ldb + (col0 + bn0);
            if (gk < K && col0 + bn0 + 8 <= N) {
                float2 v0 = *(const float2*)(Bp + 0);
                float2 v1 = *(const float2*)(Bp + 2);
                float2 v2 = *(const float2*)(Bp + 4);
                float2 v3 = *(const float2*)(Bp + 6);
                *(float4*)&Bs[bk][bn0]     = make_float4(v0.x, v0.y, v1.x, v1.y);
                *(float4*)&Bs[bk][bn0 + 4] = make_float4(v2.x, v2.y, v3.x, v3.y);
            } else {
                #pragma unroll
                for (int i = 0; i < 8; ++i) {
                    int gn = col0 + bn0 + i;
                    Bs[bk][bn0+i] = (gk < K && gn < N) ? Bp[i] : 0.f;
                }
            }
        }
        __syncthreads();
        #pragma unroll
        for (int kk = 0; kk < TKg; ++kk) {
            float a[8], b[8];
            #pragma unroll
            for (int i = 0; i < 8; ++i) a[i] = As[kk][ty*8 + i];
            #pragma unroll
            for (int j = 0; j < 8; ++j) b[j] = Bs[kk][tx*8 + j];
            #pragma unroll
            for (int i = 0; i < 8; ++i)
                #pragma unroll
                for (int j = 0; j < 8; ++j)
                    acc[i][j] += a[i] * b[j];
        }
        __syncthreads();
    }

    #pragma unroll
    for (int i = 0; i < 8; ++i) {
        int m = row0 + ty*8 + i;
        if (m >= M) continue;
        const float* tagrow = nullptr;
        if (tagW) {
            int tp = m & 15; if (tp > 8) tp = 8;   // rows are (batch, slot) for the U/V GEMMs
            tagrow = tagW + (size_t)tp * ldb;
        }
        #pragma unroll
        for (int j = 0; j < 8; ++j) {
            int n = col0 + tx*8 + j;
            if (n >= N) continue;
            float v = acc[i][j];
            if (bias)   v += bias[n];
            if (tagrow) v += tagrow[n];
            if (relu)   v = fmaxf(v, 0.f);
            C[(size_t)m * ldc + n] = v;
        }
    }
}

// H1[r=bb*128+p, c] = relu(U[bb*16 + (p&7), c] + V[bb*16 + (p>>3), c])
__global__ void pair_build(const float* __restrict__ U, const float* __restrict__ V,
                           float* __restrict__ H1, int T)
{
    int r = blockIdx.x;
    int c = blockIdx.y * 256 + threadIdx.x;
    if (c >= T) return;
    int p = r & 127;
    int bb = r >> 7;
    float u = U[((size_t)(bb*16 + (p & 7))) * T + c];
    float v = V[((size_t)(bb*16 + (p >> 3))) * T + c];
    H1[(size_t)r * T + c] = fmaxf(u + v, 0.f);
}

// rel[bb*8+a, c] = sum_{p<64} G[bb*128+p, c] + sum_{j<8} G[bb*128+64+a*8+j, c]
__global__ void reduce_pairs(const float* __restrict__ G, float* __restrict__ rel, int T)
{
    int bb = blockIdx.x;
    int c = blockIdx.y * 256 + threadIdx.x;
    if (c >= T) return;
    const float* g = G + (size_t)bb * 128 * T + c;
    float s0 = 0.f;
    #pragma unroll
    for (int p = 0; p < 64; ++p) s0 += g[(size_t)p * T];
    for (int a = 0; a < 8; ++a) {
        float s = s0;
        #pragma unroll
        for (int j = 0; j < 8; ++j) s += g[(size_t)(64 + a*8 + j) * T];
        rel[((size_t)bb * 8 + a) * T + c] = s;
    }
}

// f[row] = dot(HF[row,:], Wf2) + bf2[0]; one wave per row
__global__ void fout_kernel(const float* __restrict__ h, const float* __restrict__ Wf2,
                            const float* __restrict__ bf2, float* __restrict__ fout,
                            int rows, int T)
{
    int wid = (int)((blockIdx.x * (size_t)blockDim.x + threadIdx.x) >> 6);
    int lane = threadIdx.x & 63;
    if (wid >= rows) return;
    const float* hr = h + (size_t)wid * T;
    float s = 0.f;
    for (int c = lane; c < T; c += 64) s += hr[c] * Wf2[c];
    #pragma unroll
    for (int off = 32; off > 0; off >>= 1) s += __shfl_down(s, off, 64);
    if (lane == 0) fout[wid] = s + bf2[0];
}

// loss = mean over (512,8) of max(f,0) - f*onehot + log1p(exp(-|f|)); acc = mean(argmax==label)
__global__ void loss_kernel(const float* __restrict__ fout, const int* __restrict__ labels,
                            float* __restrict__ out)
{
    __shared__ float sl[512];
    __shared__ float sc[512];
    int b = threadIdx.x;  // 512 threads, one per batch row
    const float* f = fout + (size_t)b * 8;
    int lab = labels[b];
    float rl = 0.f;
    int best = 0;
    float bv = f[0];
    #pragma unroll
    for (int a = 0; a < 8; ++a) {
        float v = f[a];
        rl += fmaxf(v, 0.f) - v * ((a == lab) ? 1.f : 0.f) + log1pf(expf(-fabsf(v)));
        if (v > bv) { bv = v; best = a; }   // first-max semantics like np.argmax
    }
    sl[b] = rl;
    sc[b] = (best == lab) ? 1.f : 0.f;
    __syncthreads();
    for (int s = 256; s > 0; s >>= 1) {
        if (b < s) { sl[b] += sl[b + s]; sc[b] += sc[b + s]; }
        __syncthreads();
    }
    if (b == 0) { out[0] = sl[0] / 4096.f; out[1] = sc[0] / 512.f; }
}

extern "C" void kernel_launch(void* const* d_in, const int* in_sizes, int n_in,
                              void* d_out, int out_size, void* d_ws, size_t ws_size,
                              hipStream_t stream)
{
    (void)in_sizes; (void)n_in; (void)out_size;
    const float* x      = (const float*)d_in[0];
    const float* W_emb  = (const float*)d_in[1];
    const float* b_emb  = (const float*)d_in[2];
    const float* Wg1    = (const float*)d_in[3];
    const float* bg1    = (const float*)d_in[4];
    const float* Wg2    = (const float*)d_in[5];
    const float* bg2    = (const float*)d_in[6];
    const float* Wg3    = (const float*)d_in[7];
    const float* bg3    = (const float*)d_in[8];
    const float* Wf1    = (const float*)d_in[9];
    const float* bf1    = (const float*)d_in[10];
    const float* Wf2    = (const float*)d_in[11];
    const float* bf2    = (const float*)d_in[12];
    const int*   labels = (const int*)d_in[13];

    const int B = 512, S = 16, E = 6400, D = 512, T = 1042;

    auto alignup = [](size_t v) { return (v + 255) & ~(size_t)255; };

    // Pick the largest batch-chunk whose scratch fits ws_size.
    int Bc = 512;
    for (;;) {
        size_t need = alignup((size_t)B * 8 * 4);                 // fout (global)
        need += alignup((size_t)Bc * S * D * 4);                  // emb
        need += 2 * alignup((size_t)Bc * S * T * 4);              // U, V
        need += 2 * alignup((size_t)Bc * 128 * T * 4);            // H1, H2
        need += 2 * alignup((size_t)Bc * 8 * T * 4);              // REL, HF
        if (need <= ws_size || Bc == 1) break;
        Bc >>= 1;
    }

    char* p = (char*)d_ws;
    auto take = [&](size_t bytes) { char* r = p; p += (bytes + 255) & ~(size_t)255; return (float*)r; };
    float* fout = take((size_t)B * 8 * 4);
    float* emb  = take((size_t)Bc * S * D * 4);
    float* Ubuf = take((size_t)Bc * S * T * 4);
    float* Vbuf = take((size_t)Bc * S * T * 4);
    float* H1   = take((size_t)Bc * 128 * T * 4);
    float* H2   = take((size_t)Bc * 128 * T * 4);
    float* REL  = take((size_t)Bc * 8 * T * 4);
    float* HF   = take((size_t)Bc * 8 * T * 4);

    const int nch = B / Bc;
    for (int ch = 0; ch < nch; ++ch) {
        const float* xc = x + (size_t)ch * Bc * S * E;
        const int M1 = Bc * S;

        // emb = x @ W_emb + b_emb
        gemm_f32<<<dim3((D + TNg-1)/TNg, (M1 + TMg-1)/TMg), 256, 0, stream>>>(
            xc, E, W_emb, D, emb, D, M1, D, E, b_emb, nullptr, 0);

        // U = emb @ Wg1[0:512] + Wg1[512+tag] + bg1
        gemm_f32<<<dim3((T + TNg-1)/TNg, (M1 + TMg-1)/TMg), 256, 0, stream>>>(
            emb, D, Wg1, T, Ubuf, T, M1, T, D, bg1, Wg1 + (size_t)512 * T, 0);
        // V = emb @ Wg1[521:1033] + Wg1[1033+tag]
        gemm_f32<<<dim3((T + TNg-1)/TNg, (M1 + TMg-1)/TMg), 256, 0, stream>>>(
            emb, D, Wg1 + (size_t)521 * T, T, Vbuf, T, M1, T, D, nullptr, Wg1 + (size_t)1033 * T, 0);

        // H1 = relu(U[j] + V[i])
        pair_build<<<dim3(Bc * 128, (T + 255)/256), 256, 0, stream>>>(Ubuf, Vbuf, H1, T);

        const int M2 = Bc * 128;
        gemm_f32<<<dim3((T + TNg-1)/TNg, (M2 + TMg-1)/TMg), 256, 0, stream>>>(
            H1, T, Wg2, T, H2, T, M2, T, T, bg2, nullptr, 1);
        gemm_f32<<<dim3((T + TNg-1)/TNg, (M2 + TMg-1)/TMg), 256, 0, stream>>>(
            H2, T, Wg3, T, H1, T, M2, T, T, bg3, nullptr, 1);   // G -> H1 buffer

        reduce_pairs<<<dim3(Bc, (T + 255)/256), 256, 0, stream>>>(H1, REL, T);

        const int M3 = Bc * 8;
        gemm_f32<<<dim3((T + TNg-1)/TNg, (M3 + TMg-1)/TMg), 256, 0, stream>>>(
            REL, T, Wf1, T, HF, T, M3, T, T, bf1, nullptr, 1);

        fout_kernel<<<(M3 * 64 + 255)/256, 256, 0, stream>>>(
            HF, Wf2, bf2, fout + (size_t)ch * Bc * 8, M3, T);
    }

    loss_kernel<<<1, 512, 0, stream>>>(fout, labels, (float*)d_out);
}

// Round 2
// 1491.490 us; speedup vs baseline: 3.9376x; 3.9376x over previous
//
#include <hip/hip_runtime.h>
#include <hip/hip_bf16.h>
#include <math.h>

// WReN forward (loss, acc) — bf16 MFMA version.
//   emb  = bf16(x) @ bf16(W_emb)^T-staged + b_emb          -> bf16  (8192 x 512)
//   U    = emb @ Wg1[0:512]    + tagrow + bg1              -> fp32  (8192 x 1042, ld 1056)
//   V    = emb @ Wg1[521:1033] + tagrow                    -> fp32
//   H1   = bf16(relu(U[j] + V[i]))                         -> bf16  (65536 x 1056)
//   H2   = bf16(relu(H1 @ Wg2 + bg2))                      -> bf16
//   G    = bf16(relu(H2 @ Wg3 + bg3))  (overwrites H1)     -> bf16
//   REL  = bf16(sum_{p<64} G + sum_j G[64+a*8+j])          -> bf16  (4096 x 1056)
//   HF   = fp32(relu(REL @ Wf1 + bf1))                     -> fp32
//   f    = HF . Wf2 + bf2 (fp32); loss/acc fp32
// All GEMMs: 128x128 tile, BK=32, 4 waves, mfma_f32_16x16x32_bf16,
// global_load_lds width 16 (requires lda/ldb % 8 == 0 -> padded ld 1056).

typedef __bf16 bf16;
typedef __bf16 v8bf __attribute__((ext_vector_type(8)));
typedef float  v4f  __attribute__((ext_vector_type(4)));

#define GAS(p) ((const __attribute__((address_space(1))) void*)(p))
#define LAS(p) ((__attribute__((address_space(3))) void*)(p))

// ---------------------------------------------------------------------------
// C = A(MxK) @ Bt(NxK)^T, fp32 accumulate. M%128==0. K%32==0. lda,ldb %8==0.
// Bt rows must be allocated (and zeroed) up to gridDim.x*128.
// Epilogue: cols < Nreal get bias/tag/relu; cols [Nreal,Nstore) get 0;
// cols >= Nstore are skipped. Output fp32 or bf16.
__global__ __launch_bounds__(256) void gemm_bf16(
    const bf16* __restrict__ A, int lda,
    const bf16* __restrict__ Bt, int ldb,
    void* __restrict__ C, int ldc, int out_is_bf16,
    int M, int Nreal, int Nstore, int K,
    const float* __restrict__ bias,
    const float* __restrict__ tagW, int tag_ld,
    int relu)
{
    __shared__ bf16 As[128 * 32];
    __shared__ bf16 Bs[128 * 32];

    const int tid  = threadIdx.x;
    const int wv   = tid >> 6;
    const int lane = tid & 63;
    const int quad = lane >> 4;
    const int l15  = lane & 15;
    const int row0 = blockIdx.y * 128;
    const int col0 = blockIdx.x * 128;
    const int wm0  = (wv >> 1) * 64;
    const int wn0  = (wv & 1) * 64;

    v4f acc[4][4] = {};

    // staging: wave wv covers tile rows [wv*32, wv*32+32) as 2 chunks of 16 rows.
    // lane l of a chunk: row = base + (l>>2), k-offset = (l&3)*8  (16B each).
    const int srow  = wv * 32 + (lane >> 2);
    const int skoff = (lane & 3) * 8;
    const bf16* ga = A  + (size_t)(row0 + srow) * lda + skoff;
    const bf16* gb = Bt + (size_t)(col0 + srow) * ldb + skoff;
    bf16* laA = &As[(wv * 32) * 32];   // wave-uniform LDS base; HW adds lane*16B
    bf16* laB = &Bs[(wv * 32) * 32];

    for (int k0 = 0; k0 < K; k0 += 32) {
        __builtin_amdgcn_global_load_lds(GAS(ga),                    LAS(laA),            16, 0, 0);
        __builtin_amdgcn_global_load_lds(GAS(ga + (size_t)16 * lda), LAS(laA + 16 * 32),  16, 0, 0);
        __builtin_amdgcn_global_load_lds(GAS(gb),                    LAS(laB),            16, 0, 0);
        __builtin_amdgcn_global_load_lds(GAS(gb + (size_t)16 * ldb), LAS(laB + 16 * 32),  16, 0, 0);
        ga += 32; gb += 32;
        __syncthreads();

        v8bf af[4], bf[4];
        #pragma unroll
        for (int i = 0; i < 4; ++i)
            af[i] = *(const v8bf*)&As[(wm0 + i * 16 + l15) * 32 + quad * 8];
        #pragma unroll
        for (int j = 0; j < 4; ++j)
            bf[j] = *(const v8bf*)&Bs[(wn0 + j * 16 + l15) * 32 + quad * 8];
        #pragma unroll
        for (int i = 0; i < 4; ++i)
            #pragma unroll
            for (int j = 0; j < 4; ++j)
                acc[i][j] = __builtin_amdgcn_mfma_f32_16x16x32_bf16(af[i], bf[j], acc[i][j], 0, 0, 0);
        __syncthreads();
    }

    // epilogue: C/D layout col=lane&15, row=quad*4+reg  [m89/m91-verified]
    #pragma unroll
    for (int j = 0; j < 4; ++j) {
        int col = col0 + wn0 + j * 16 + l15;
        if (col >= Nstore) continue;
        float badd = (col < Nreal && bias) ? bias[col] : 0.f;
        #pragma unroll
        for (int i = 0; i < 4; ++i) {
            #pragma unroll
            for (int r = 0; r < 4; ++r) {
                int row = row0 + wm0 + i * 16 + quad * 4 + r;
                float v = 0.f;
                if (col < Nreal) {
                    v = acc[i][j][r] + badd;
                    if (tagW) {
                        int tp = row & 15; if (tp > 8) tp = 8;
                        v += tagW[(size_t)tp * tag_ld + col];
                    }
                    if (relu) v = fmaxf(v, 0.f);
                }
                if (out_is_bf16) ((bf16*)C)[(size_t)row * ldc + col] = (bf16)v;
                else             ((float*)C)[(size_t)row * ldc + col] = v;
            }
        }
    }
}

// ---------------------------------------------------------------------------
// Bt[n*ldb + k] = (k < krows && n < ncols) ? W[(k)*ldw + n] : 0   (cast to bf16)
// grid: (ceil(kalloc/32), ceil(nalloc/32)), block (32,8). Zero-fills pads.
__global__ void transpose_cast(const float* __restrict__ W, int ldw,
                               int krows, int ncols,
                               bf16* __restrict__ Bt, int ldb,
                               int nalloc, int kalloc)
{
    __shared__ float t[32][33];
    int kb = blockIdx.x * 32;
    int nb = blockIdx.y * 32;
    int tx = threadIdx.x, ty = threadIdx.y;
    #pragma unroll
    for (int i = 0; i < 4; ++i) {
        int k = kb + ty + i * 8, n = nb + tx;
        t[ty + i * 8][tx] = (k < krows && n < ncols) ? W[(size_t)k * ldw + n] : 0.f;
    }
    __syncthreads();
    #pragma unroll
    for (int i = 0; i < 4; ++i) {
        int n = nb + ty + i * 8, k = kb + tx;
        if (n < nalloc && k < kalloc)
            Bt[(size_t)n * ldb + k] = (bf16)t[tx][ty + i * 8];
    }
}

// out[i] = bf16(in[i]), vectorized x4. n4 = n/4.
__global__ void cast_bf16_vec(const float* __restrict__ in, bf16* __restrict__ out, size_t n4)
{
    size_t i = blockIdx.x * (size_t)blockDim.x + threadIdx.x;
    if (i >= n4) return;
    float4 v = ((const float4*)in)[i];
    union { bf16 h[4]; unsigned long long q; } o;
    o.h[0] = (bf16)v.x; o.h[1] = (bf16)v.y; o.h[2] = (bf16)v.z; o.h[3] = (bf16)v.w;
    *(unsigned long long*)&out[i * 4] = o.q;
}

// H1[r, c] = bf16(relu(U[bb*16+(p&7), c] + V[bb*16+(p>>3), c])), r = bb*128+p
__global__ void pair_build(const float* __restrict__ U, const float* __restrict__ V,
                           bf16* __restrict__ H1, int ldp)
{
    int r  = blockIdx.x;
    int c4 = blockIdx.y * blockDim.x + threadIdx.x;
    if (c4 >= (ldp >> 2)) return;
    int p = r & 127, bb = r >> 7;
    float4 u = *(const float4*)&U[(size_t)(bb * 16 + (p & 7)) * ldp + c4 * 4];
    float4 v = *(const float4*)&V[(size_t)(bb * 16 + (p >> 3)) * ldp + c4 * 4];
    union { bf16 h[4]; unsigned long long q; } o;
    o.h[0] = (bf16)fmaxf(u.x + v.x, 0.f);
    o.h[1] = (bf16)fmaxf(u.y + v.y, 0.f);
    o.h[2] = (bf16)fmaxf(u.z + v.z, 0.f);
    o.h[3] = (bf16)fmaxf(u.w + v.w, 0.f);
    *(unsigned long long*)&H1[(size_t)r * ldp + c4 * 4] = o.q;
}

// rel[bb*8+a, c] = sum_{p<64} G[bb*128+p, c] + sum_{j<8} G[bb*128+64+a*8+j, c]
__global__ void reduce_pairs(const bf16* __restrict__ G, bf16* __restrict__ rel, int ldp)
{
    int bb = blockIdx.x;
    int c4 = blockIdx.y * blockDim.x + threadIdx.x;
    if (c4 >= (ldp >> 2)) return;
    const bf16* g = G + (size_t)bb * 128 * ldp + c4 * 4;
    float s0[4] = {0.f, 0.f, 0.f, 0.f};
    for (int p = 0; p < 64; ++p) {
        union { unsigned long long q; bf16 h[4]; } t;
        t.q = *(const unsigned long long*)&g[(size_t)p * ldp];
        s0[0] += (float)t.h[0]; s0[1] += (float)t.h[1];
        s0[2] += (float)t.h[2]; s0[3] += (float)t.h[3];
    }
    for (int a = 0; a < 8; ++a) {
        float s[4] = {s0[0], s0[1], s0[2], s0[3]};
        #pragma unroll
        for (int j = 0; j < 8; ++j) {
            union { unsigned long long q; bf16 h[4]; } t;
            t.q = *(const unsigned long long*)&g[(size_t)(64 + a * 8 + j) * ldp];
            s[0] += (float)t.h[0]; s[1] += (float)t.h[1];
            s[2] += (float)t.h[2]; s[3] += (float)t.h[3];
        }
        union { bf16 h[4]; unsigned long long q; } o;
        o.h[0] = (bf16)s[0]; o.h[1] = (bf16)s[1]; o.h[2] = (bf16)s[2]; o.h[3] = (bf16)s[3];
        *(unsigned long long*)&rel[((size_t)bb * 8 + a) * ldp + c4 * 4] = o.q;
    }
}

// f[row] = dot(HF[row, 0..T), Wf2) + bf2[0]; one wave per row. HF fp32, ld ldp.
__global__ void fout_kernel(const float* __restrict__ h, const float* __restrict__ Wf2,
                            const float* __restrict__ bf2, float* __restrict__ fout,
                            int rows, int T, int ldp)
{
    int wid  = (int)((blockIdx.x * (size_t)blockDim.x + threadIdx.x) >> 6);
    int lane = threadIdx.x & 63;
    if (wid >= rows) return;
    const float* hr = h + (size_t)wid * ldp;
    float s = 0.f;
    for (int c = lane; c < T; c += 64) s += hr[c] * Wf2[c];
    #pragma unroll
    for (int off = 32; off > 0; off >>= 1) s += __shfl_down(s, off, 64);
    if (lane == 0) fout[wid] = s + bf2[0];
}

__global__ void loss_kernel(const float* __restrict__ fout, const int* __restrict__ labels,
                            float* __restrict__ out)
{
    __shared__ float sl[512];
    __shared__ float sc[512];
    int b = threadIdx.x;
    const float* f = fout + (size_t)b * 8;
    int lab = labels[b];
    float rl = 0.f;
    int best = 0;
    float bv = f[0];
    #pragma unroll
    for (int a = 0; a < 8; ++a) {
        float v = f[a];
        rl += fmaxf(v, 0.f) - v * ((a == lab) ? 1.f : 0.f) + log1pf(expf(-fabsf(v)));
        if (v > bv) { bv = v; best = a; }
    }
    sl[b] = rl;
    sc[b] = (best == lab) ? 1.f : 0.f;
    __syncthreads();
    for (int s = 256; s > 0; s >>= 1) {
        if (b < s) { sl[b] += sl[b + s]; sc[b] += sc[b + s]; }
        __syncthreads();
    }
    if (b == 0) { out[0] = sl[0] / 4096.f; out[1] = sc[0] / 512.f; }
}

// ---------------------------------------------------------------------------
extern "C" void kernel_launch(void* const* d_in, const int* in_sizes, int n_in,
                              void* d_out, int out_size, void* d_ws, size_t ws_size,
                              hipStream_t stream)
{
    (void)in_sizes; (void)n_in; (void)out_size;
    const float* x      = (const float*)d_in[0];
    const float* W_emb  = (const float*)d_in[1];
    const float* b_emb  = (const float*)d_in[2];
    const float* Wg1    = (const float*)d_in[3];
    const float* bg1    = (const float*)d_in[4];
    const float* Wg2    = (const float*)d_in[5];
    const float* bg2    = (const float*)d_in[6];
    const float* Wg3    = (const float*)d_in[7];
    const float* bg3    = (const float*)d_in[8];
    const float* Wf1    = (const float*)d_in[9];
    const float* bf1    = (const float*)d_in[10];
    const float* Wf2    = (const float*)d_in[11];
    const float* bf2    = (const float*)d_in[12];
    const int*   labels = (const int*)d_in[13];

    const int B = 512, S = 16, E = 6400, D = 512, T = 1042;
    const int TP = 1056;   // padded K / col dim (mult of 32, mult of 8)
    const int NA = 1152;   // padded N rows for Bt buffers (9 tiles * 128)

    auto alignup = [](size_t v) { return (v + 255) & ~(size_t)255; };

    // fixed buffers
    size_t fixed = alignup((size_t)B * 8 * 4)            // fout
                 + alignup((size_t)D * E * 2)            // W_embT (512 x 6400)
                 + 2 * alignup((size_t)NA * D * 2)       // W1aT, W1bT (1152 x 512)
                 + 3 * alignup((size_t)NA * TP * 2);     // Wg2T, Wg3T, Wf1T

    int Bc = 512;
    for (;;) {
        size_t need = fixed
            + alignup((size_t)Bc * S * E * 2)            // xb
            + alignup((size_t)Bc * S * D * 2)            // emb (bf16)
            + 2 * alignup((size_t)Bc * S * TP * 4)       // U, V (fp32)
            + 2 * alignup((size_t)Bc * 128 * TP * 2)     // H1, H2 (bf16)
            + alignup((size_t)Bc * 8 * TP * 2)           // REL (bf16)
            + alignup((size_t)Bc * 8 * TP * 4);          // HF (fp32)
        if (need <= ws_size || Bc == 16) break;
        Bc >>= 1;
    }

    char* p = (char*)d_ws;
    auto take = [&](size_t bytes) -> void* {
        char* r = p; p += (bytes + 255) & ~(size_t)255; return r;
    };
    float* fout  = (float*)take((size_t)B * 8 * 4);
    bf16* W_embT = (bf16*)take((size_t)D * E * 2);
    bf16* W1aT   = (bf16*)take((size_t)NA * D * 2);
    bf16* W1bT   = (bf16*)take((size_t)NA * D * 2);
    bf16* Wg2T   = (bf16*)take((size_t)NA * TP * 2);
    bf16* Wg3T   = (bf16*)take((size_t)NA * TP * 2);
    bf16* Wf1T   = (bf16*)take((size_t)NA * TP * 2);
    bf16* xb     = (bf16*)take((size_t)Bc * S * E * 2);
    bf16* embB   = (bf16*)take((size_t)Bc * S * D * 2);
    float* Ubuf  = (float*)take((size_t)Bc * S * TP * 4);
    float* Vbuf  = (float*)take((size_t)Bc * S * TP * 4);
    bf16* H1     = (bf16*)take((size_t)Bc * 128 * TP * 2);
    bf16* H2     = (bf16*)take((size_t)Bc * 128 * TP * 2);
    bf16* REL    = (bf16*)take((size_t)Bc * 8 * TP * 2);
    float* HF    = (float*)take((size_t)Bc * 8 * TP * 4);

    dim3 tb(32, 8);
    // weight prep (once per launch; ws is re-poisoned before every call)
    transpose_cast<<<dim3(E / 32, D / 32), tb, 0, stream>>>(W_emb, D, E, D, W_embT, E, D, E);
    transpose_cast<<<dim3(D / 32, NA / 32), tb, 0, stream>>>(Wg1,                   T, D, T, W1aT, D, NA, D);
    transpose_cast<<<dim3(D / 32, NA / 32), tb, 0, stream>>>(Wg1 + (size_t)521 * T, T, D, T, W1bT, D, NA, D);
    transpose_cast<<<dim3(TP / 32, NA / 32), tb, 0, stream>>>(Wg2, T, T, T, Wg2T, TP, NA, TP);
    transpose_cast<<<dim3(TP / 32, NA / 32), tb, 0, stream>>>(Wg3, T, T, T, Wg3T, TP, NA, TP);
    transpose_cast<<<dim3(TP / 32, NA / 32), tb, 0, stream>>>(Wf1, T, T, T, Wf1T, TP, NA, TP);

    const int nch = B / Bc;
    for (int ch = 0; ch < nch; ++ch) {
        const int M1 = Bc * S, M2 = Bc * 128, M3 = Bc * 8;

        size_t nx4 = (size_t)Bc * S * E / 4;
        cast_bf16_vec<<<(int)((nx4 + 255) / 256), 256, 0, stream>>>(
            x + (size_t)ch * Bc * S * E, xb, nx4);

        // emb = bf16(x) @ W_emb + b_emb  -> bf16 (ld 512)
        gemm_bf16<<<dim3(D / 128, M1 / 128), 256, 0, stream>>>(
            xb, E, W_embT, E, embB, D, 1, M1, D, D, E, b_emb, nullptr, 0, 0);

        // U = emb @ Wg1[0:512] + Wg1[512+tag] + bg1  -> fp32 (ld TP)
        gemm_bf16<<<dim3(NA / 128, M1 / 128), 256, 0, stream>>>(
            embB, D, W1aT, D, Ubuf, TP, 0, M1, T, TP, D, bg1, Wg1 + (size_t)512 * T, T, 0);
        // V = emb @ Wg1[521:1033] + Wg1[1033+tag]    -> fp32
        gemm_bf16<<<dim3(NA / 128, M1 / 128), 256, 0, stream>>>(
            embB, D, W1bT, D, Vbuf, TP, 0, M1, T, TP, D, nullptr, Wg1 + (size_t)1033 * T, T, 0);

        pair_build<<<dim3(M2, (TP / 4 + 255) / 256), 256, 0, stream>>>(Ubuf, Vbuf, H1, TP);

        // H2 = relu(H1 @ Wg2 + bg2) -> bf16
        gemm_bf16<<<dim3(NA / 128, M2 / 128), 256, 0, stream>>>(
            H1, TP, Wg2T, TP, H2, TP, 1, M2, T, TP, TP, bg2, nullptr, 0, 1);
        // G = relu(H2 @ Wg3 + bg3) -> bf16 (into H1)
        gemm_bf16<<<dim3(NA / 128, M2 / 128), 256, 0, stream>>>(
            H2, TP, Wg3T, TP, H1, TP, 1, M2, T, TP, TP, bg3, nullptr, 0, 1);

        reduce_pairs<<<dim3(Bc, (TP / 4 + 255) / 256), 256, 0, stream>>>(H1, REL, TP);

        // HF = relu(REL @ Wf1 + bf1) -> fp32
        gemm_bf16<<<dim3(NA / 128, M3 / 128), 256, 0, stream>>>(
            REL, TP, Wf1T, TP, HF, TP, 0, M3, T, TP, TP, bf1, nullptr, 0, 1);

        fout_kernel<<<(M3 * 64 + 255) / 256, 256, 0, stream>>>(
            HF, Wf2, bf2, fout + (size_t)ch * Bc * 8, M3, T, TP);
    }

    loss_kernel<<<1, 512, 0, stream>>>(fout, labels, (float*)d_out);
}

// Round 3
// 1404.337 us; speedup vs baseline: 4.1819x; 1.0621x over previous
//
#include <hip/hip_runtime.h>
#include <hip/hip_bf16.h>
#include <math.h>

// WReN forward (loss, acc) — bf16 MFMA + XCD-aware swizzle.
//   emb  = bf16(x) @ W_embT + b_emb                        -> bf16  (8192 x 512)
//   U    = emb @ Wg1[0:512]    + tagrow + bg1              -> bf16  (8192 x 1056)
//   V    = emb @ Wg1[521:1033] + tagrow                    -> bf16
//   H1   = bf16(relu(U[j] + V[i]))                         -> bf16  (65536 x 1056)
//   H2   = bf16(relu(H1 @ Wg2 + bg2))                      -> bf16
//   G    = bf16(relu(H2 @ Wg3 + bg3))  (overwrites H1)     -> bf16
//   REL  = bf16(sum_{p<64} G + sum_j G[64+a*8+j])          -> bf16  (4096 x 1056)
//   HF   = fp32(relu(REL @ Wf1 + bf1))                     -> fp32
//   f    = HF . Wf2 + bf2 (fp32); loss/acc fp32
// GEMM: 128x128 tile, BK=32, 4 waves, mfma_f32_16x16x32_bf16,
// global_load_lds width 16. 1-D grid with XCD swizzle: blocks L -> XCD L&7;
// each XCD owns Mt/8 contiguous M-tiles and iterates all Nt N-tiles within,
// so the A row-panel lands in ONE per-XCD L2 and is reused Nt times
// (round-2 profile: FETCH 747 MB vs 140 MB ideal = cross-XCD A refetch).

typedef __bf16 bf16;
typedef __bf16 v8bf __attribute__((ext_vector_type(8)));
typedef float  v4f  __attribute__((ext_vector_type(4)));

#define GAS(p) ((const __attribute__((address_space(1))) void*)(p))
#define LAS(p) ((__attribute__((address_space(3))) void*)(p))

// ---------------------------------------------------------------------------
// C = A(MxK) @ Bt(Ntx128 x K)^T. M = Mt*128 (Mt%8==0), K%32==0, lda/ldb %8==0.
// Bt rows allocated+zeroed up to Nt*128. Epilogue: col<Nreal gets
// bias/tag/relu; [Nreal,Nstore) gets 0; >=Nstore skipped.
__global__ __launch_bounds__(256) void gemm_bf16(
    const bf16* __restrict__ A, int lda,
    const bf16* __restrict__ Bt, int ldb,
    void* __restrict__ C, int ldc, int out_is_bf16,
    int Mt, int Nt,
    int Nreal, int Nstore, int K,
    const float* __restrict__ bias,
    const float* __restrict__ tagW, int tag_ld,
    int relu)
{
    __shared__ bf16 As[128 * 32];
    __shared__ bf16 Bs[128 * 32];

    // XCD swizzle: consecutive linear ids round-robin across 8 XCDs; give
    // each XCD a contiguous M band, N fastest within it.
    const int L    = blockIdx.x;
    const int xcd  = L & 7;
    const int idx  = L >> 3;
    const int mlee = idx / Nt;
    const int n    = idx - mlee * Nt;
    const int m    = xcd * (Mt >> 3) + mlee;
    const int row0 = m * 128;
    const int col0 = n * 128;

    const int tid  = threadIdx.x;
    const int wv   = tid >> 6;
    const int lane = tid & 63;
    const int quad = lane >> 4;
    const int l15  = lane & 15;
    const int wm0  = (wv >> 1) * 64;
    const int wn0  = (wv & 1) * 64;

    v4f acc[4][4] = {};

    const int srow  = wv * 32 + (lane >> 2);
    const int skoff = (lane & 3) * 8;
    const bf16* ga = A  + (size_t)(row0 + srow) * lda + skoff;
    const bf16* gb = Bt + (size_t)(col0 + srow) * ldb + skoff;
    bf16* laA = &As[(wv * 32) * 32];
    bf16* laB = &Bs[(wv * 32) * 32];

    for (int k0 = 0; k0 < K; k0 += 32) {
        __builtin_amdgcn_global_load_lds(GAS(ga),                    LAS(laA),           16, 0, 0);
        __builtin_amdgcn_global_load_lds(GAS(ga + (size_t)16 * lda), LAS(laA + 16 * 32), 16, 0, 0);
        __builtin_amdgcn_global_load_lds(GAS(gb),                    LAS(laB),           16, 0, 0);
        __builtin_amdgcn_global_load_lds(GAS(gb + (size_t)16 * ldb), LAS(laB + 16 * 32), 16, 0, 0);
        ga += 32; gb += 32;
        __syncthreads();

        v8bf af[4], bf[4];
        #pragma unroll
        for (int i = 0; i < 4; ++i)
            af[i] = *(const v8bf*)&As[(wm0 + i * 16 + l15) * 32 + quad * 8];
        #pragma unroll
        for (int j = 0; j < 4; ++j)
            bf[j] = *(const v8bf*)&Bs[(wn0 + j * 16 + l15) * 32 + quad * 8];
        #pragma unroll
        for (int i = 0; i < 4; ++i)
            #pragma unroll
            for (int j = 0; j < 4; ++j)
                acc[i][j] = __builtin_amdgcn_mfma_f32_16x16x32_bf16(af[i], bf[j], acc[i][j], 0, 0, 0);
        __syncthreads();
    }

    // epilogue: C/D layout col=lane&15, row=quad*4+reg  [m89/m91-verified]
    #pragma unroll
    for (int j = 0; j < 4; ++j) {
        int col = col0 + wn0 + j * 16 + l15;
        if (col >= Nstore) continue;
        float badd = (col < Nreal && bias) ? bias[col] : 0.f;
        #pragma unroll
        for (int i = 0; i < 4; ++i) {
            #pragma unroll
            for (int r = 0; r < 4; ++r) {
                int row = row0 + wm0 + i * 16 + quad * 4 + r;
                float v = 0.f;
                if (col < Nreal) {
                    v = acc[i][j][r] + badd;
                    if (tagW) {
                        int tp = row & 15; if (tp > 8) tp = 8;
                        v += tagW[(size_t)tp * tag_ld + col];
                    }
                    if (relu) v = fmaxf(v, 0.f);
                }
                if (out_is_bf16) ((bf16*)C)[(size_t)row * ldc + col] = (bf16)v;
                else             ((float*)C)[(size_t)row * ldc + col] = v;
            }
        }
    }
}

// ---------------------------------------------------------------------------
__global__ void transpose_cast(const float* __restrict__ W, int ldw,
                               int krows, int ncols,
                               bf16* __restrict__ Bt, int ldb,
                               int nalloc, int kalloc)
{
    __shared__ float t[32][33];
    int kb = blockIdx.x * 32;
    int nb = blockIdx.y * 32;
    int tx = threadIdx.x, ty = threadIdx.y;
    #pragma unroll
    for (int i = 0; i < 4; ++i) {
        int k = kb + ty + i * 8, n = nb + tx;
        t[ty + i * 8][tx] = (k < krows && n < ncols) ? W[(size_t)k * ldw + n] : 0.f;
    }
    __syncthreads();
    #pragma unroll
    for (int i = 0; i < 4; ++i) {
        int n = nb + ty + i * 8, k = kb + tx;
        if (n < nalloc && k < kalloc)
            Bt[(size_t)n * ldb + k] = (bf16)t[tx][ty + i * 8];
    }
}

__global__ void cast_bf16_vec(const float* __restrict__ in, bf16* __restrict__ out, size_t n4)
{
    size_t i = blockIdx.x * (size_t)blockDim.x + threadIdx.x;
    if (i >= n4) return;
    float4 v = ((const float4*)in)[i];
    union { bf16 h[4]; unsigned long long q; } o;
    o.h[0] = (bf16)v.x; o.h[1] = (bf16)v.y; o.h[2] = (bf16)v.z; o.h[3] = (bf16)v.w;
    *(unsigned long long*)&out[i * 4] = o.q;
}

// H1[r, c] = bf16(relu(U[bb*16+(p&7), c] + V[bb*16+(p>>3), c])), r = bb*128+p
// U,V bf16; 8-wide vectors (16B).
__global__ void pair_build(const bf16* __restrict__ U, const bf16* __restrict__ V,
                           bf16* __restrict__ H1, int ldp)
{
    int r  = blockIdx.x;
    int c8 = blockIdx.y * blockDim.x + threadIdx.x;
    if (c8 >= (ldp >> 3)) return;
    int p = r & 127, bb = r >> 7;
    v8bf u = *(const v8bf*)&U[(size_t)(bb * 16 + (p & 7)) * ldp + c8 * 8];
    v8bf v = *(const v8bf*)&V[(size_t)(bb * 16 + (p >> 3)) * ldp + c8 * 8];
    v8bf o;
    #pragma unroll
    for (int i = 0; i < 8; ++i)
        o[i] = (bf16)fmaxf((float)u[i] + (float)v[i], 0.f);
    *(v8bf*)&H1[(size_t)r * ldp + c8 * 8] = o;
}

// rel[bb*8+a, c] = sum_{p<64} G[bb*128+p, c] + sum_{j<8} G[bb*128+64+a*8+j, c]
__global__ void reduce_pairs(const bf16* __restrict__ G, bf16* __restrict__ rel, int ldp)
{
    int bb = blockIdx.x;
    int c4 = blockIdx.y * blockDim.x + threadIdx.x;
    if (c4 >= (ldp >> 2)) return;
    const bf16* g = G + (size_t)bb * 128 * ldp + c4 * 4;
    float s0[4] = {0.f, 0.f, 0.f, 0.f};
    for (int p = 0; p < 64; ++p) {
        union { unsigned long long q; bf16 h[4]; } t;
        t.q = *(const unsigned long long*)&g[(size_t)p * ldp];
        s0[0] += (float)t.h[0]; s0[1] += (float)t.h[1];
        s0[2] += (float)t.h[2]; s0[3] += (float)t.h[3];
    }
    for (int a = 0; a < 8; ++a) {
        float s[4] = {s0[0], s0[1], s0[2], s0[3]};
        #pragma unroll
        for (int j = 0; j < 8; ++j) {
            union { unsigned long long q; bf16 h[4]; } t;
            t.q = *(const unsigned long long*)&g[(size_t)(64 + a * 8 + j) * ldp];
            s[0] += (float)t.h[0]; s[1] += (float)t.h[1];
            s[2] += (float)t.h[2]; s[3] += (float)t.h[3];
        }
        union { bf16 h[4]; unsigned long long q; } o;
        o.h[0] = (bf16)s[0]; o.h[1] = (bf16)s[1]; o.h[2] = (bf16)s[2]; o.h[3] = (bf16)s[3];
        *(unsigned long long*)&rel[((size_t)bb * 8 + a) * ldp + c4 * 4] = o.q;
    }
}

__global__ void fout_kernel(const float* __restrict__ h, const float* __restrict__ Wf2,
                            const float* __restrict__ bf2, float* __restrict__ fout,
                            int rows, int T, int ldp)
{
    int wid  = (int)((blockIdx.x * (size_t)blockDim.x + threadIdx.x) >> 6);
    int lane = threadIdx.x & 63;
    if (wid >= rows) return;
    const float* hr = h + (size_t)wid * ldp;
    float s = 0.f;
    for (int c = lane; c < T; c += 64) s += hr[c] * Wf2[c];
    #pragma unroll
    for (int off = 32; off > 0; off >>= 1) s += __shfl_down(s, off, 64);
    if (lane == 0) fout[wid] = s + bf2[0];
}

__global__ void loss_kernel(const float* __restrict__ fout, const int* __restrict__ labels,
                            float* __restrict__ out)
{
    __shared__ float sl[512];
    __shared__ float sc[512];
    int b = threadIdx.x;
    const float* f = fout + (size_t)b * 8;
    int lab = labels[b];
    float rl = 0.f;
    int best = 0;
    float bv = f[0];
    #pragma unroll
    for (int a = 0; a < 8; ++a) {
        float v = f[a];
        rl += fmaxf(v, 0.f) - v * ((a == lab) ? 1.f : 0.f) + log1pf(expf(-fabsf(v)));
        if (v > bv) { bv = v; best = a; }
    }
    sl[b] = rl;
    sc[b] = (best == lab) ? 1.f : 0.f;
    __syncthreads();
    for (int s = 256; s > 0; s >>= 1) {
        if (b < s) { sl[b] += sl[b + s]; sc[b] += sc[b + s]; }
        __syncthreads();
    }
    if (b == 0) { out[0] = sl[0] / 4096.f; out[1] = sc[0] / 512.f; }
}

// ---------------------------------------------------------------------------
extern "C" void kernel_launch(void* const* d_in, const int* in_sizes, int n_in,
                              void* d_out, int out_size, void* d_ws, size_t ws_size,
                              hipStream_t stream)
{
    (void)in_sizes; (void)n_in; (void)out_size;
    const float* x      = (const float*)d_in[0];
    const float* W_emb  = (const float*)d_in[1];
    const float* b_emb  = (const float*)d_in[2];
    const float* Wg1    = (const float*)d_in[3];
    const float* bg1    = (const float*)d_in[4];
    const float* Wg2    = (const float*)d_in[5];
    const float* bg2    = (const float*)d_in[6];
    const float* Wg3    = (const float*)d_in[7];
    const float* bg3    = (const float*)d_in[8];
    const float* Wf1    = (const float*)d_in[9];
    const float* bf1    = (const float*)d_in[10];
    const float* Wf2    = (const float*)d_in[11];
    const float* bf2    = (const float*)d_in[12];
    const int*   labels = (const int*)d_in[13];

    const int B = 512, S = 16, E = 6400, D = 512, T = 1042;
    const int TP = 1056;   // padded K/col dim (mult of 32 and 8)
    const int NA = 1152;   // padded Bt rows (9 tiles * 128)

    auto alignup = [](size_t v) { return (v + 255) & ~(size_t)255; };

    size_t fixed = alignup((size_t)B * 8 * 4)
                 + alignup((size_t)D * E * 2)
                 + 2 * alignup((size_t)NA * D * 2)
                 + 3 * alignup((size_t)NA * TP * 2);

    int Bc = 512;
    for (;;) {
        size_t need = fixed
            + alignup((size_t)Bc * S * E * 2)            // xb
            + alignup((size_t)Bc * S * D * 2)            // emb bf16
            + 2 * alignup((size_t)Bc * S * TP * 2)       // U, V bf16
            + 2 * alignup((size_t)Bc * 128 * TP * 2)     // H1, H2
            + alignup((size_t)Bc * 8 * TP * 2)           // REL
            + alignup((size_t)Bc * 8 * TP * 4);          // HF
        if (need <= ws_size || Bc == 16) break;
        Bc >>= 1;
    }

    char* p = (char*)d_ws;
    auto take = [&](size_t bytes) -> void* {
        char* r = p; p += (bytes + 255) & ~(size_t)255; return r;
    };
    float* fout  = (float*)take((size_t)B * 8 * 4);
    bf16* W_embT = (bf16*)take((size_t)D * E * 2);
    bf16* W1aT   = (bf16*)take((size_t)NA * D * 2);
    bf16* W1bT   = (bf16*)take((size_t)NA * D * 2);
    bf16* Wg2T   = (bf16*)take((size_t)NA * TP * 2);
    bf16* Wg3T   = (bf16*)take((size_t)NA * TP * 2);
    bf16* Wf1T   = (bf16*)take((size_t)NA * TP * 2);
    bf16* xb     = (bf16*)take((size_t)Bc * S * E * 2);
    bf16* embB   = (bf16*)take((size_t)Bc * S * D * 2);
    bf16* Ubuf   = (bf16*)take((size_t)Bc * S * TP * 2);
    bf16* Vbuf   = (bf16*)take((size_t)Bc * S * TP * 2);
    bf16* H1     = (bf16*)take((size_t)Bc * 128 * TP * 2);
    bf16* H2     = (bf16*)take((size_t)Bc * 128 * TP * 2);
    bf16* REL    = (bf16*)take((size_t)Bc * 8 * TP * 2);
    float* HF    = (float*)take((size_t)Bc * 8 * TP * 4);

    dim3 tb(32, 8);
    transpose_cast<<<dim3(E / 32, D / 32), tb, 0, stream>>>(W_emb, D, E, D, W_embT, E, D, E);
    transpose_cast<<<dim3(D / 32, NA / 32), tb, 0, stream>>>(Wg1,                   T, D, T, W1aT, D, NA, D);
    transpose_cast<<<dim3(D / 32, NA / 32), tb, 0, stream>>>(Wg1 + (size_t)521 * T, T, D, T, W1bT, D, NA, D);
    transpose_cast<<<dim3(TP / 32, NA / 32), tb, 0, stream>>>(Wg2, T, T, T, Wg2T, TP, NA, TP);
    transpose_cast<<<dim3(TP / 32, NA / 32), tb, 0, stream>>>(Wg3, T, T, T, Wg3T, TP, NA, TP);
    transpose_cast<<<dim3(TP / 32, NA / 32), tb, 0, stream>>>(Wf1, T, T, T, Wf1T, TP, NA, TP);

    const int nch = B / Bc;
    for (int ch = 0; ch < nch; ++ch) {
        const int M1t = Bc * S / 128, M2t = Bc, M3t = Bc * 8 / 128;

        size_t nx4 = (size_t)Bc * S * E / 4;
        cast_bf16_vec<<<(int)((nx4 + 255) / 256), 256, 0, stream>>>(
            x + (size_t)ch * Bc * S * E, xb, nx4);

        // emb = bf16(x) @ W_emb + b_emb -> bf16 (ld 512)
        gemm_bf16<<<M1t * (D / 128), 256, 0, stream>>>(
            xb, E, W_embT, E, embB, D, 1, M1t, D / 128, D, D, E, b_emb, nullptr, 0, 0);

        // U = emb @ Wg1[0:512] + tag + bg1 -> bf16
        gemm_bf16<<<M1t * (NA / 128), 256, 0, stream>>>(
            embB, D, W1aT, D, Ubuf, TP, 1, M1t, NA / 128, T, TP, D, bg1, Wg1 + (size_t)512 * T, T, 0);
        // V = emb @ Wg1[521:1033] + tag -> bf16
        gemm_bf16<<<M1t * (NA / 128), 256, 0, stream>>>(
            embB, D, W1bT, D, Vbuf, TP, 1, M1t, NA / 128, T, TP, D, nullptr, Wg1 + (size_t)1033 * T, T, 0);

        pair_build<<<dim3(Bc * 128, (TP / 8 + 255) / 256), 256, 0, stream>>>(Ubuf, Vbuf, H1, TP);

        // H2 = relu(H1 @ Wg2 + bg2) -> bf16
        gemm_bf16<<<M2t * (NA / 128), 256, 0, stream>>>(
            H1, TP, Wg2T, TP, H2, TP, 1, M2t, NA / 128, T, TP, TP, bg2, nullptr, 0, 1);
        // G = relu(H2 @ Wg3 + bg3) -> bf16 (into H1)
        gemm_bf16<<<M2t * (NA / 128), 256, 0, stream>>>(
            H2, TP, Wg3T, TP, H1, TP, 1, M2t, NA / 128, T, TP, TP, bg3, nullptr, 0, 1);

        reduce_pairs<<<dim3(Bc, (TP / 4 + 255) / 256), 256, 0, stream>>>(H1, REL, TP);

        // HF = relu(REL @ Wf1 + bf1) -> fp32
        gemm_bf16<<<M3t * (NA / 128), 256, 0, stream>>>(
            REL, TP, Wf1T, TP, HF, TP, 0, M3t, NA / 128, T, TP, TP, bf1, nullptr, 0, 1);

        fout_kernel<<<(Bc * 8 * 64 + 255) / 256, 256, 0, stream>>>(
            HF, Wf2, bf2, fout + (size_t)ch * Bc * 8, Bc * 8, T, TP);
    }

    loss_kernel<<<1, 512, 0, stream>>>(fout, labels, (float*)d_out);
}

// Round 4
// 1228.035 us; speedup vs baseline: 4.7823x; 1.1436x over previous
//
#include <hip/hip_runtime.h>
#include <hip/hip_bf16.h>
#include <math.h>

// WReN forward (loss, acc) — bf16 MFMA, XCD swizzle, LDS-routed epilogue,
// fused relation-reduction in GEMM-3.
//   emb  = bf16(x) @ W_embT + b_emb                        -> bf16  (8192 x 512)
//   U    = emb @ Wg1[0:512]    + tagrow + bg1              -> bf16  (8192 x 1056)
//   V    = emb @ Wg1[521:1033] + tagrow                    -> bf16
//   H1   = bf16(relu(U[j] + V[i]))                         -> bf16  (65536 x 1056)
//   H2   = bf16(relu(H1 @ Wg2 + bg2))                      -> bf16
//   REL  = fused: per M-tile (== one batch elem's 128 pairs) reduce
//          relu(H2 @ Wg3 + bg3) rows ->  s_ctx + s_a       -> bf16  (4096 x 1056)
//   HF   = bf16(relu(REL @ Wf1 + bf1))
//   f    = HF . Wf2 + bf2 (fp32); loss/acc fp32
// Round-3 lesson: FETCH dropped 747->138 MB with no time change -> GEMMs are
// pipeline-bound on the per-block tail (64 scalar 2B stores/thread, WRITE 2x
// amplified). This round vectorizes the epilogue via LDS and fuses the pair
// reduction so G is never materialized.

typedef __bf16 bf16;
typedef __bf16 v8bf __attribute__((ext_vector_type(8)));
typedef float  v4f  __attribute__((ext_vector_type(4)));
typedef unsigned long long u64;

#define GAS(p) ((const __attribute__((address_space(1))) void*)(p))
#define LAS(p) ((__attribute__((address_space(3))) void*)(p))

// ---------------------------------------------------------------------------
// C = A(MxK) @ Bt(Ntx128 x K)^T. M = Mt*128 (Mt%8==0), K%32==0, lda/ldb %8==0.
// mode 0: store bf16 C tile (col<Nreal: bias/tag/relu; [Nreal,Nstore): 0).
// mode 1: fused relation reduce — tile rows are pairs p of batch elem bb==m;
//         writes REL[bb*8+a][col] = sum_{p<64} + sum_{p in group a}.
__global__ __launch_bounds__(256) void gemm_bf16(
    const bf16* __restrict__ A, int lda,
    const bf16* __restrict__ Bt, int ldb,
    bf16* __restrict__ C, int ldc,
    int Mt, int Nt,
    int Nreal, int Nstore, int K,
    const float* __restrict__ bias,
    const float* __restrict__ tagW, int tag_ld,
    int relu, int mode)
{
    __shared__ bf16 As[128 * 32];
    __shared__ bf16 Bs[128 * 32];
    __shared__ bf16 Epi[64 * 132];   // 64-row half-tile, stride 132 (pad)

    // XCD swizzle: consecutive linear ids round-robin across 8 XCDs; each XCD
    // owns a contiguous M band, N fastest -> A row-panel reused Nt x in one L2.
    const int L    = blockIdx.x;
    const int xcd  = L & 7;
    const int idx  = L >> 3;
    const int mlee = idx / Nt;
    const int n    = idx - mlee * Nt;
    const int m    = xcd * (Mt >> 3) + mlee;
    const int row0 = m * 128;
    const int col0 = n * 128;

    const int tid  = threadIdx.x;
    const int wv   = tid >> 6;
    const int lane = tid & 63;
    const int quad = lane >> 4;
    const int l15  = lane & 15;
    const int wm0  = (wv >> 1) * 64;
    const int wn0  = (wv & 1) * 64;

    v4f acc[4][4] = {};

    const int srow  = wv * 32 + (lane >> 2);
    const int skoff = (lane & 3) * 8;
    const bf16* ga = A  + (size_t)(row0 + srow) * lda + skoff;
    const bf16* gb = Bt + (size_t)(col0 + srow) * ldb + skoff;
    bf16* laA = &As[(wv * 32) * 32];
    bf16* laB = &Bs[(wv * 32) * 32];

    for (int k0 = 0; k0 < K; k0 += 32) {
        __builtin_amdgcn_global_load_lds(GAS(ga),                    LAS(laA),           16, 0, 0);
        __builtin_amdgcn_global_load_lds(GAS(ga + (size_t)16 * lda), LAS(laA + 16 * 32), 16, 0, 0);
        __builtin_amdgcn_global_load_lds(GAS(gb),                    LAS(laB),           16, 0, 0);
        __builtin_amdgcn_global_load_lds(GAS(gb + (size_t)16 * ldb), LAS(laB + 16 * 32), 16, 0, 0);
        ga += 32; gb += 32;
        __syncthreads();

        v8bf af[4], bf[4];
        #pragma unroll
        for (int i = 0; i < 4; ++i)
            af[i] = *(const v8bf*)&As[(wm0 + i * 16 + l15) * 32 + quad * 8];
        #pragma unroll
        for (int j = 0; j < 4; ++j)
            bf[j] = *(const v8bf*)&Bs[(wn0 + j * 16 + l15) * 32 + quad * 8];
        #pragma unroll
        for (int i = 0; i < 4; ++i)
            #pragma unroll
            for (int j = 0; j < 4; ++j)
                acc[i][j] = __builtin_amdgcn_mfma_f32_16x16x32_bf16(af[i], bf[j], acc[i][j], 0, 0, 0);
        __syncthreads();
    }

    // ---- epilogue ----
    // per-thread bias for its 4 fragment columns
    float bcol[4];
    #pragma unroll
    for (int j = 0; j < 4; ++j) {
        int col = col0 + wn0 + j * 16 + l15;
        bcol[j] = (col < Nreal && bias) ? bias[col] : 0.f;
    }

    float s_ctx = 0.f;   // mode-1 state, persists across passes (tid<128)

    #pragma unroll
    for (int pass = 0; pass < 2; ++pass) {
        // fragment -> LDS (bf16, final values). C/D layout: col=lane&15,
        // row=quad*4+reg [m89/m91-verified]. Waves {0,1} hold rows 0..63,
        // waves {2,3} rows 64..127.
        if (wm0 == pass * 64) {
            #pragma unroll
            for (int i = 0; i < 4; ++i) {
                #pragma unroll
                for (int j = 0; j < 4; ++j) {
                    #pragma unroll
                    for (int r = 0; r < 4; ++r) {
                        int lrow = i * 16 + quad * 4 + r;
                        int lcol = wn0 + j * 16 + l15;
                        int col  = col0 + lcol;
                        float v = 0.f;
                        if (col < Nreal) {
                            v = acc[i][j][r] + bcol[j];
                            if (tagW) {
                                int row = row0 + pass * 64 + lrow;
                                int tp = row & 15; if (tp > 8) tp = 8;
                                v += tagW[(size_t)tp * tag_ld + col];
                            }
                            if (relu) v = fmaxf(v, 0.f);
                        }
                        Epi[lrow * 132 + lcol] = (bf16)v;
                    }
                }
            }
        }
        __syncthreads();

        if (mode == 0) {
            // copy 64x128 half-tile out with 16B stores
            int lrow = tid >> 2;
            int cg   = (tid & 3) * 32;
            int grow = row0 + pass * 64 + lrow;
            #pragma unroll
            for (int k = 0; k < 4; ++k) {
                int c = cg + k * 8;
                int gcol = col0 + c;
                if (gcol < Nstore) {
                    u64 q0 = *(const u64*)&Epi[lrow * 132 + c];
                    u64 q1 = *(const u64*)&Epi[lrow * 132 + c + 4];
                    uint4 st;
                    st.x = (unsigned)q0; st.y = (unsigned)(q0 >> 32);
                    st.z = (unsigned)q1; st.w = (unsigned)(q1 >> 32);
                    *(uint4*)&C[(size_t)grow * ldc + gcol] = st;
                }
            }
        } else {
            // fused relation reduce: pass 0 rows = p 0..63 (ctx pairs),
            // pass 1 rows = p 64..127 (answer groups a = row>>3).
            if (tid < 128) {
                int col = tid;
                if (pass == 0) {
                    float s = 0.f;
                    for (int r = 0; r < 64; ++r) s += (float)Epi[r * 132 + col];
                    s_ctx = s;
                } else {
                    float sA[8] = {};
                    for (int r = 0; r < 64; ++r) sA[r >> 3] += (float)Epi[r * 132 + col];
                    int gcol = col0 + col;
                    if (gcol < Nstore) {
                        #pragma unroll
                        for (int a = 0; a < 8; ++a)
                            C[(size_t)(m * 8 + a) * ldc + gcol] = (bf16)(s_ctx + sA[a]);
                    }
                }
            }
        }
        __syncthreads();
    }
}

// ---------------------------------------------------------------------------
__global__ void transpose_cast(const float* __restrict__ W, int ldw,
                               int krows, int ncols,
                               bf16* __restrict__ Bt, int ldb,
                               int nalloc, int kalloc)
{
    __shared__ float t[32][33];
    int kb = blockIdx.x * 32;
    int nb = blockIdx.y * 32;
    int tx = threadIdx.x, ty = threadIdx.y;
    #pragma unroll
    for (int i = 0; i < 4; ++i) {
        int k = kb + ty + i * 8, n = nb + tx;
        t[ty + i * 8][tx] = (k < krows && n < ncols) ? W[(size_t)k * ldw + n] : 0.f;
    }
    __syncthreads();
    #pragma unroll
    for (int i = 0; i < 4; ++i) {
        int n = nb + ty + i * 8, k = kb + tx;
        if (n < nalloc && k < kalloc)
            Bt[(size_t)n * ldb + k] = (bf16)t[tx][ty + i * 8];
    }
}

__global__ void cast_bf16_vec(const float* __restrict__ in, bf16* __restrict__ out, size_t n4)
{
    size_t i = blockIdx.x * (size_t)blockDim.x + threadIdx.x;
    if (i >= n4) return;
    float4 v = ((const float4*)in)[i];
    union { bf16 h[4]; u64 q; } o;
    o.h[0] = (bf16)v.x; o.h[1] = (bf16)v.y; o.h[2] = (bf16)v.z; o.h[3] = (bf16)v.w;
    *(u64*)&out[i * 4] = o.q;
}

// H1[r, c8*8..] = bf16(relu(U[bb*16+(p&7)] + V[bb*16+(p>>3)])), r = bb*128+p
// block = 128 threads, one row per block; threads cover 132 8-col chunks.
__global__ void pair_build(const bf16* __restrict__ U, const bf16* __restrict__ V,
                           bf16* __restrict__ H1, int ldp)
{
    int r = blockIdx.x;
    int p = r & 127, bb = r >> 7;
    const bf16* ur = U + (size_t)(bb * 16 + (p & 7)) * ldp;
    const bf16* vr = V + (size_t)(bb * 16 + (p >> 3)) * ldp;
    bf16* hr = H1 + (size_t)r * ldp;
    int nch = ldp >> 3;
    for (int c8 = threadIdx.x; c8 < nch; c8 += blockDim.x) {
        v8bf u = *(const v8bf*)&ur[c8 * 8];
        v8bf v = *(const v8bf*)&vr[c8 * 8];
        v8bf o;
        #pragma unroll
        for (int i = 0; i < 8; ++i)
            o[i] = (bf16)fmaxf((float)u[i] + (float)v[i], 0.f);
        *(v8bf*)&hr[c8 * 8] = o;
    }
}

__global__ void fout_kernel(const bf16* __restrict__ h, const float* __restrict__ Wf2,
                            const float* __restrict__ bf2, float* __restrict__ fout,
                            int rows, int T, int ldp)
{
    int wid  = (int)((blockIdx.x * (size_t)blockDim.x + threadIdx.x) >> 6);
    int lane = threadIdx.x & 63;
    if (wid >= rows) return;
    const bf16* hr = h + (size_t)wid * ldp;
    float s = 0.f;
    for (int c = lane; c < T; c += 64) s += (float)hr[c] * Wf2[c];
    #pragma unroll
    for (int off = 32; off > 0; off >>= 1) s += __shfl_down(s, off, 64);
    if (lane == 0) fout[wid] = s + bf2[0];
}

__global__ void loss_kernel(const float* __restrict__ fout, const int* __restrict__ labels,
                            float* __restrict__ out)
{
    __shared__ float sl[512];
    __shared__ float sc[512];
    int b = threadIdx.x;
    const float* f = fout + (size_t)b * 8;
    int lab = labels[b];
    float rl = 0.f;
    int best = 0;
    float bv = f[0];
    #pragma unroll
    for (int a = 0; a < 8; ++a) {
        float v = f[a];
        rl += fmaxf(v, 0.f) - v * ((a == lab) ? 1.f : 0.f) + log1pf(expf(-fabsf(v)));
        if (v > bv) { bv = v; best = a; }
    }
    sl[b] = rl;
    sc[b] = (best == lab) ? 1.f : 0.f;
    __syncthreads();
    for (int s = 256; s > 0; s >>= 1) {
        if (b < s) { sl[b] += sl[b + s]; sc[b] += sc[b + s]; }
        __syncthreads();
    }
    if (b == 0) { out[0] = sl[0] / 4096.f; out[1] = sc[0] / 512.f; }
}

// ---------------------------------------------------------------------------
extern "C" void kernel_launch(void* const* d_in, const int* in_sizes, int n_in,
                              void* d_out, int out_size, void* d_ws, size_t ws_size,
                              hipStream_t stream)
{
    (void)in_sizes; (void)n_in; (void)out_size;
    const float* x      = (const float*)d_in[0];
    const float* W_emb  = (const float*)d_in[1];
    const float* b_emb  = (const float*)d_in[2];
    const float* Wg1    = (const float*)d_in[3];
    const float* bg1    = (const float*)d_in[4];
    const float* Wg2    = (const float*)d_in[5];
    const float* bg2    = (const float*)d_in[6];
    const float* Wg3    = (const float*)d_in[7];
    const float* bg3    = (const float*)d_in[8];
    const float* Wf1    = (const float*)d_in[9];
    const float* bf1    = (const float*)d_in[10];
    const float* Wf2    = (const float*)d_in[11];
    const float* bf2    = (const float*)d_in[12];
    const int*   labels = (const int*)d_in[13];

    const int B = 512, S = 16, E = 6400, D = 512, T = 1042;
    const int TP = 1056;   // padded K/col dim (mult of 32 and 8)
    const int NA = 1152;   // padded Bt rows (9 tiles * 128)

    auto alignup = [](size_t v) { return (v + 255) & ~(size_t)255; };

    size_t fixed = alignup((size_t)B * 8 * 4)
                 + alignup((size_t)D * E * 2)
                 + 2 * alignup((size_t)NA * D * 2)
                 + 3 * alignup((size_t)NA * TP * 2);

    int Bc = 512;
    for (;;) {
        size_t need = fixed
            + alignup((size_t)Bc * S * E * 2)            // xb
            + alignup((size_t)Bc * S * D * 2)            // emb bf16
            + 2 * alignup((size_t)Bc * S * TP * 2)       // U, V bf16
            + 2 * alignup((size_t)Bc * 128 * TP * 2)     // H1, H2
            + alignup((size_t)Bc * 8 * TP * 2)           // REL
            + alignup((size_t)Bc * 8 * TP * 2);          // HF (bf16 now)
        if (need <= ws_size || Bc == 16) break;
        Bc >>= 1;
    }

    char* p = (char*)d_ws;
    auto take = [&](size_t bytes) -> void* {
        char* r = p; p += (bytes + 255) & ~(size_t)255; return r;
    };
    float* fout  = (float*)take((size_t)B * 8 * 4);
    bf16* W_embT = (bf16*)take((size_t)D * E * 2);
    bf16* W1aT   = (bf16*)take((size_t)NA * D * 2);
    bf16* W1bT   = (bf16*)take((size_t)NA * D * 2);
    bf16* Wg2T   = (bf16*)take((size_t)NA * TP * 2);
    bf16* Wg3T   = (bf16*)take((size_t)NA * TP * 2);
    bf16* Wf1T   = (bf16*)take((size_t)NA * TP * 2);
    bf16* xb     = (bf16*)take((size_t)Bc * S * E * 2);
    bf16* embB   = (bf16*)take((size_t)Bc * S * D * 2);
    bf16* Ubuf   = (bf16*)take((size_t)Bc * S * TP * 2);
    bf16* Vbuf   = (bf16*)take((size_t)Bc * S * TP * 2);
    bf16* H1     = (bf16*)take((size_t)Bc * 128 * TP * 2);
    bf16* H2     = (bf16*)take((size_t)Bc * 128 * TP * 2);
    bf16* REL    = (bf16*)take((size_t)Bc * 8 * TP * 2);
    bf16* HF     = (bf16*)take((size_t)Bc * 8 * TP * 2);

    dim3 tb(32, 8);
    transpose_cast<<<dim3(E / 32, D / 32), tb, 0, stream>>>(W_emb, D, E, D, W_embT, E, D, E);
    transpose_cast<<<dim3(D / 32, NA / 32), tb, 0, stream>>>(Wg1,                   T, D, T, W1aT, D, NA, D);
    transpose_cast<<<dim3(D / 32, NA / 32), tb, 0, stream>>>(Wg1 + (size_t)521 * T, T, D, T, W1bT, D, NA, D);
    transpose_cast<<<dim3(TP / 32, NA / 32), tb, 0, stream>>>(Wg2, T, T, T, Wg2T, TP, NA, TP);
    transpose_cast<<<dim3(TP / 32, NA / 32), tb, 0, stream>>>(Wg3, T, T, T, Wg3T, TP, NA, TP);
    transpose_cast<<<dim3(TP / 32, NA / 32), tb, 0, stream>>>(Wf1, T, T, T, Wf1T, TP, NA, TP);

    const int nch = B / Bc;
    for (int ch = 0; ch < nch; ++ch) {
        const int M1t = Bc * S / 128, M2t = Bc, M3t = Bc * 8 / 128;

        size_t nx4 = (size_t)Bc * S * E / 4;
        cast_bf16_vec<<<(int)((nx4 + 255) / 256), 256, 0, stream>>>(
            x + (size_t)ch * Bc * S * E, xb, nx4);

        // emb = bf16(x) @ W_emb + b_emb -> bf16 (ld 512)
        gemm_bf16<<<M1t * (D / 128), 256, 0, stream>>>(
            xb, E, W_embT, E, embB, D, M1t, D / 128, D, D, E, b_emb, nullptr, 0, 0, 0);

        // U = emb @ Wg1[0:512] + tag + bg1 -> bf16
        gemm_bf16<<<M1t * (NA / 128), 256, 0, stream>>>(
            embB, D, W1aT, D, Ubuf, TP, M1t, NA / 128, T, TP, D, bg1, Wg1 + (size_t)512 * T, T, 0, 0);
        // V = emb @ Wg1[521:1033] + tag -> bf16
        gemm_bf16<<<M1t * (NA / 128), 256, 0, stream>>>(
            embB, D, W1bT, D, Vbuf, TP, M1t, NA / 128, T, TP, D, nullptr, Wg1 + (size_t)1033 * T, T, 0, 0);

        pair_build<<<Bc * 128, 128, 0, stream>>>(Ubuf, Vbuf, H1, TP);

        // H2 = relu(H1 @ Wg2 + bg2) -> bf16
        gemm_bf16<<<M2t * (NA / 128), 256, 0, stream>>>(
            H1, TP, Wg2T, TP, H2, TP, M2t, NA / 128, T, TP, TP, bg2, nullptr, 0, 1, 0);
        // REL = fused reduce of relu(H2 @ Wg3 + bg3)  (G never materialized)
        gemm_bf16<<<M2t * (NA / 128), 256, 0, stream>>>(
            H2, TP, Wg3T, TP, REL, TP, M2t, NA / 128, T, TP, TP, bg3, nullptr, 0, 1, 1);

        // HF = relu(REL @ Wf1 + bf1) -> bf16
        gemm_bf16<<<M3t * (NA / 128), 256, 0, stream>>>(
            REL, TP, Wf1T, TP, HF, TP, M3t, NA / 128, T, TP, TP, bf1, nullptr, 0, 1, 0);

        fout_kernel<<<(Bc * 8 * 64 + 255) / 256, 256, 0, stream>>>(
            HF, Wf2, bf2, fout + (size_t)ch * Bc * 8, Bc * 8, T, TP);
    }

    loss_kernel<<<1, 512, 0, stream>>>(fout, labels, (float*)d_out);
}